// Round 1
// baseline (676.043 us; speedup 1.0000x reference)
//
#include <hip/hip_runtime.h>
#include <stdint.h>

#define B_  16
#define QL  2048
#define KL  2048
#define FD  128
#define BQ  64
#define BK  32
#define NSTEP (KL/BK)

#define KSTR  136        // K-tile LDS row stride (shorts)
#define VTOFF 4352       // 32*136
#define VTSTR 36         // V^T LDS row stride (shorts); b128 reads conflict-free
#define BUFS  8960       // 4352 + 128*36 shorts per buffer
#define WS_HALF (B_*KL*FD)   // shorts per converted array (8 MB)

typedef __attribute__((ext_vector_type(8))) short bf16x8;
typedef __attribute__((ext_vector_type(4))) float f32x4;
typedef __attribute__((ext_vector_type(4))) int   i32x4;
typedef __attribute__((ext_vector_type(4))) unsigned int u32x4;

__device__ __forceinline__ unsigned short f2b(float f) {
  union { float f; unsigned u; } x; x.f = f;
  return (unsigned short)((x.u + 0x8000u) >> 16);
}

// pack two f32 -> one dword of two bf16 (lo = first arg)
__device__ __forceinline__ unsigned cvt_pk_bf16(float lo, float hi) {
  unsigned r;
  asm("v_cvt_pk_bf16_f32 %0, %1, %2" : "=v"(r) : "v"(lo), "v"(hi));
  return r;
}

// ---- pre-pass 1: K fp32 -> bf16, same layout ----
__global__ __launch_bounds__(256) void conv_k(const float* __restrict__ kp,
                                              unsigned short* __restrict__ kb) {
  int idx = (blockIdx.x * 256 + threadIdx.x) * 4;
  float4 u = *(const float4*)(kp + idx);
  ushort4 s4; s4.x = f2b(u.x); s4.y = f2b(u.y); s4.z = f2b(u.z); s4.w = f2b(u.w);
  *(ushort4*)(kb + idx) = s4;
}

// ---- pre-pass 2: V fp32 [b][k][f] -> bf16 tiled-transposed [b][kt][f][32] ----
__global__ __launch_bounds__(256) void conv_vt(const float* __restrict__ vp,
                                               unsigned short* __restrict__ vt) {
  __shared__ float tl[32 * 132];
  const int t = threadIdx.x, b = blockIdx.x >> 6, kt = blockIdx.x & 63;
  const int r = t >> 3, f0 = (t & 7) * 16;
  const float* src = vp + ((long long)(b * KL + kt * 32 + r)) * FD + f0;
  #pragma unroll
  for (int i = 0; i < 4; ++i)
    *(float4*)&tl[r * 132 + f0 + 4 * i] = *(const float4*)(src + 4 * i);
  __syncthreads();
  const int f = t >> 1, half = t & 1;
  bf16x8 o0, o1;
  #pragma unroll
  for (int j = 0; j < 8; ++j)  o0[j] = (short)f2b(tl[(half * 16 + j) * 132 + f]);
  #pragma unroll
  for (int j = 0; j < 8; ++j)  o1[j] = (short)f2b(tl[(half * 16 + 8 + j) * 132 + f]);
  unsigned short* dst = vt + ((long long)((b * 64 + kt) * FD + f)) * 32 + half * 16;
  *(bf16x8*)dst = o0;
  *(bf16x8*)(dst + 8) = o1;
}

// out = (sum_k !attn*e^s*V)/l - sum_k !attn*!alibi*d*bscale*V,  l = sum_k e^s
//
// SWAPPED QK^T: S = mfma(K,Q) puts C rows on the k-axis, cols on q. Each lane
// owns ONE q-row (q = l15) and k_local = s*16 + 4*q4 + r. Consequences:
//  - masks load as per-lane int4 (k on the register axis): 16 -> 4 VMEM/step
//  - softmax denominator is a lane-local scalar (no per-r reduction state)
//  - P/T -> PV A-frag transpose happens IN REGISTER: cvt_pk_bf16 pairs +
//    8 ds_bpermute + 4 cndmask per matrix. No plds buffer, no mid-step
//    lgkmcnt(0) convoy. LDS drops 46 KB -> 35.8 KB.
// K/V keep the dist-2 register pipeline + lgkm-only raw barrier (in-flight
// VMEM crosses the barrier).
__global__ __launch_bounds__(256, 2) void alibi_attn(
    const unsigned short* __restrict__ kbp,   // bf16 K [b][k][f]
    const unsigned short* __restrict__ vtp,   // bf16 V^T tiles [b][kt][f][32]
    const float* __restrict__ qp,
    const float* __restrict__ cqp,
    const float* __restrict__ ckp,
    const int* __restrict__ amp,
    const int* __restrict__ almp,
    const float* __restrict__ bsp,
    const float* __restrict__ rmp,
    float* __restrict__ outp)
{
  __shared__ unsigned short kv[2 * BUFS];            // 35 KB K + V^T dbuf

  const int t    = threadIdx.x;
  const int w    = t >> 6;
  const int lane = t & 63;
  const int l15  = lane & 15;
  const int q4   = lane >> 4;

  const int bid  = blockIdx.x;
  const int xcd  = bid & 7, slot = bid >> 3;
  const int b    = (xcd << 1) | (slot >> 5);
  const int qbase = (slot & 31) * BQ;

  const float bscale = bsp[0] / rmp[0];
  const float sl2 = 0.08838834764831845f * 1.44269504089f;  // scale*log2(e)

  const int kr_st = t >> 3, kc_st = (t & 7) * 16;  // K staging
  const int vf_st = t >> 1, vh_st = (t & 1) * 16;  // V staging

  // ---- prologue: Q tile -> LDS buf0 (transient), grab B-frags + coords ----
  {
    const float* qg = qp + ((long long)(b * QL + qbase)) * FD;
    #pragma unroll
    for (int i = 0; i < 8; ++i) {
      int idx = t + 256 * i;
      float4 u = ((const float4*)qg)[idx];
      int row = idx >> 5, col = (idx & 31) * 4;
      ushort4 s4; s4.x = f2b(u.x); s4.y = f2b(u.y); s4.z = f2b(u.z); s4.w = f2b(u.w);
      *(ushort4*)&kv[row * KSTR + col] = s4;
    }
  }
  __syncthreads();
  bf16x8 qfrag[4];
  {
    const int m = w * 16 + l15;
    #pragma unroll
    for (int fs = 0; fs < 4; ++fs)
      qfrag[fs] = *(const bf16x8*)&kv[m * KSTR + fs * 32 + q4 * 8];
  }
  // this lane's q-row (swapped layout: q = l15 within the wave's 16 rows)
  const int qrow = qbase + w * 16 + l15;
  float cqx, cqy;
  {
    float2 c2 = *(const float2*)(cqp + ((long long)(b * QL + qrow)) * 2);
    cqx = c2.x; cqy = c2.y;
  }
  const long long mrow = (long long)(b * QL + qrow) * KL;
  __syncthreads();

  const unsigned short* kgb = kbp + (long long)b * KL * FD;
  const unsigned short* vgb = vtp + (long long)b * KL * FD;

  // ---- masks/coords step 0 (regs), K/V tile 0 -> LDS buf0, tile 1 -> regs ----
  i32x4 amv[2][2], alv[2][2];          // [set][s], component r
  f32x4 ckf[2][2][2];                  // [set][s][pair(r>>1)]: (x,y,x,y)
  bf16x8 kreg[2][2], vreg[2][2];
  const int klane0 = 4 * q4;           // lane's k_local base (s adds 16)
  #pragma unroll
  for (int s = 0; s < 2; ++s) {
    const int k0 = s * 16 + klane0;
    amv[0][s] = __builtin_nontemporal_load((const i32x4*)(amp + mrow + k0));
    alv[0][s] = __builtin_nontemporal_load((const i32x4*)(almp + mrow + k0));
    ckf[0][s][0] = *(const f32x4*)(ckp + ((long long)(b * KL + k0)) * 2);
    ckf[0][s][1] = *(const f32x4*)(ckp + ((long long)(b * KL + k0)) * 2 + 4);
  }
  {
    bf16x8 k0l = *(const bf16x8*)(kgb + kr_st * FD + kc_st);
    bf16x8 k1l = *(const bf16x8*)(kgb + kr_st * FD + kc_st + 8);
    bf16x8 v0l = *(const bf16x8*)(vgb + t * 16);
    bf16x8 v1l = *(const bf16x8*)(vgb + t * 16 + 8);
    *(bf16x8*)&kv[kr_st * KSTR + kc_st]     = k0l;
    *(bf16x8*)&kv[kr_st * KSTR + kc_st + 8] = k1l;
    *(bf16x8*)&kv[VTOFF + vf_st * VTSTR + vh_st]     = v0l;
    *(bf16x8*)&kv[VTOFF + vf_st * VTSTR + vh_st + 8] = v1l;
    // tile 1 into register set 1 (drained at bottom of body 0)
    kreg[1][0] = *(const bf16x8*)(kgb + (BK + kr_st) * FD + kc_st);
    kreg[1][1] = *(const bf16x8*)(kgb + (BK + kr_st) * FD + kc_st + 8);
    vreg[1][0] = *(const bf16x8*)(vgb + BK * FD + t * 16);
    vreg[1][1] = *(const bf16x8*)(vgb + BK * FD + t * 16 + 8);
  }
  __syncthreads();

  f32x4 O1[8], O2[8];
  #pragma unroll
  for (int n = 0; n < 8; ++n) {
    O1[n] = (f32x4){0.f, 0.f, 0.f, 0.f};
    O2[n] = (f32x4){0.f, 0.f, 0.f, 0.f};
  }
  float lsum = 0.f;

  // cross-lane gather sources for the in-register P/T transpose
  const int srcA = l15 + ((q4 & 1) << 5);
  const int srcB = srcA + 16;
  const bool lowhalf = (q4 < 2);

  #pragma unroll 2
  for (int kt = 0; kt < NSTEP; ++kt) {
    const int cur = kt & 1, nxt = cur ^ 1;
    const unsigned short* kb = kv + cur * BUFS;
    unsigned short*       nb = kv + nxt * BUFS;

    // ---- fill reg set `cur` with tile kt+2 (consumed 2 bodies later) ----
    const int ktf = (kt + 2 < NSTEP) ? (kt + 2) : (NSTEP - 1);
    kreg[cur][0] = *(const bf16x8*)(kgb + (ktf * BK + kr_st) * FD + kc_st);
    kreg[cur][1] = *(const bf16x8*)(kgb + (ktf * BK + kr_st) * FD + kc_st + 8);
    vreg[cur][0] = *(const bf16x8*)(vgb + ktf * (BK * FD) + t * 16);
    vreg[cur][1] = *(const bf16x8*)(vgb + ktf * (BK * FD) + t * 16 + 8);

    // ---- masks + coords for step kt+1 (dist-1, vector loads) ----
    const int ktm = (kt + 1 < NSTEP) ? (kt + 1) : kt;
    #pragma unroll
    for (int s = 0; s < 2; ++s) {
      const int kg = ktm * BK + s * 16 + klane0;
      amv[nxt][s] = __builtin_nontemporal_load((const i32x4*)(amp + mrow + kg));
      alv[nxt][s] = __builtin_nontemporal_load((const i32x4*)(almp + mrow + kg));
      ckf[nxt][s][0] = *(const f32x4*)(ckp + ((long long)(b * KL + kg)) * 2);
      ckf[nxt][s][1] = *(const f32x4*)(ckp + ((long long)(b * KL + kg)) * 2 + 4);
    }

    // ---- QK^T (SWAPPED: A=K, B=Q) over F=128 from LDS buf cur ----
    // lane holds S[k = s*16 + 4*q4 + r][q = l15]
    f32x4 S0 = (f32x4){0.f, 0.f, 0.f, 0.f};
    f32x4 S1 = (f32x4){0.f, 0.f, 0.f, 0.f};
    #pragma unroll
    for (int fs = 0; fs < 4; ++fs) {
      bf16x8 kb0 = *(const bf16x8*)&kb[(l15)      * KSTR + fs * 32 + q4 * 8];
      bf16x8 kb1 = *(const bf16x8*)&kb[(16 + l15) * KSTR + fs * 32 + q4 * 8];
      S0 = __builtin_amdgcn_mfma_f32_16x16x32_bf16(kb0, qfrag[fs], S0, 0, 0, 0);
      S1 = __builtin_amdgcn_mfma_f32_16x16x32_bf16(kb1, qfrag[fs], S1, 0, 0, 0);
    }

    // ---- transform (all 8 elements belong to q = qrow) ----
    float wvv[2][4], tvv[2][4];
    #pragma unroll
    for (int s = 0; s < 2; ++s) {
      const f32x4 Sv = s ? S1 : S0;
      #pragma unroll
      for (int r = 0; r < 4; ++r) {
        float e = __builtin_amdgcn_exp2f(Sv[r] * sl2);
        lsum += e;
        const float ckx = ckf[cur][s][r >> 1][(r & 1) * 2];
        const float cky = ckf[cur][s][r >> 1][(r & 1) * 2 + 1];
        float dx = cqx - ckx, dy = cqy - cky;
        float d  = sqrtf(fmaf(dx, dx, dy * dy)) * bscale;
        int am = amv[cur][s][r], al = alv[cur][s][r];
        wvv[s][r] = am ? 0.f : e;
        tvv[s][r] = (am | al) ? 0.f : d;
      }
    }

    // ---- pack to bf16 + in-register transpose into PV A-frag layout ----
    // source lane (l15,g) holds X0=(k=4g,4g+1) X1=(4g+2,4g+3) X2=(16+4g,..) X3
    // target lane (l15,q4) wants k = 8*q4 + [0..7]:
    //   W0,W1 from src lane l15+32*(q4&1); W2,W3 from +16; X0/X1 if q4<2 else X2/X3
    unsigned aX0 = cvt_pk_bf16(wvv[0][0], wvv[0][1]);
    unsigned aX1 = cvt_pk_bf16(wvv[0][2], wvv[0][3]);
    unsigned aX2 = cvt_pk_bf16(wvv[1][0], wvv[1][1]);
    unsigned aX3 = cvt_pk_bf16(wvv[1][2], wvv[1][3]);
    unsigned tX0 = cvt_pk_bf16(tvv[0][0], tvv[0][1]);
    unsigned tX1 = cvt_pk_bf16(tvv[0][2], tvv[0][3]);
    unsigned tX2 = cvt_pk_bf16(tvv[1][0], tvv[1][1]);
    unsigned tX3 = cvt_pk_bf16(tvv[1][2], tvv[1][3]);

    u32x4 wa, ta;
    {
      int y0, y2;
      y0 = __shfl((int)aX0, srcA); y2 = __shfl((int)aX2, srcA);
      wa[0] = (unsigned)(lowhalf ? y0 : y2);
      y0 = __shfl((int)aX1, srcA); y2 = __shfl((int)aX3, srcA);
      wa[1] = (unsigned)(lowhalf ? y0 : y2);
      y0 = __shfl((int)aX0, srcB); y2 = __shfl((int)aX2, srcB);
      wa[2] = (unsigned)(lowhalf ? y0 : y2);
      y0 = __shfl((int)aX1, srcB); y2 = __shfl((int)aX3, srcB);
      wa[3] = (unsigned)(lowhalf ? y0 : y2);
      y0 = __shfl((int)tX0, srcA); y2 = __shfl((int)tX2, srcA);
      ta[0] = (unsigned)(lowhalf ? y0 : y2);
      y0 = __shfl((int)tX1, srcA); y2 = __shfl((int)tX3, srcA);
      ta[1] = (unsigned)(lowhalf ? y0 : y2);
      y0 = __shfl((int)tX0, srcB); y2 = __shfl((int)tX2, srcB);
      ta[2] = (unsigned)(lowhalf ? y0 : y2);
      y0 = __shfl((int)tX1, srcB); y2 = __shfl((int)tX3, srcB);
      ta[3] = (unsigned)(lowhalf ? y0 : y2);
    }
    bf16x8 aw = __builtin_bit_cast(bf16x8, wa);
    bf16x8 at = __builtin_bit_cast(bf16x8, ta);

    // ---- PV from LDS buf cur ----
    #pragma unroll
    for (int n = 0; n < 8; ++n) {
      bf16x8 vb = *(const bf16x8*)&kb[VTOFF + (n * 16 + l15) * VTSTR + q4 * 8];
      O1[n] = __builtin_amdgcn_mfma_f32_16x16x32_bf16(aw, vb, O1[n], 0, 0, 0);
      O2[n] = __builtin_amdgcn_mfma_f32_16x16x32_bf16(at, vb, O2[n], 0, 0, 0);
    }

    // ---- drain reg set `nxt` (tile kt+1, loaded 2 bodies ago) into LDS nxt ----
    *(bf16x8*)&nb[kr_st * KSTR + kc_st]     = kreg[nxt][0];
    *(bf16x8*)&nb[kr_st * KSTR + kc_st + 8] = kreg[nxt][1];
    *(bf16x8*)&nb[VTOFF + vf_st * VTSTR + vh_st]     = vreg[nxt][0];
    *(bf16x8*)&nb[VTOFF + vf_st * VTSTR + vh_st + 8] = vreg[nxt][1];

    // barrier draining ONLY LDS: in-flight VMEM prefetches survive
    asm volatile("s_waitcnt lgkmcnt(0)\n\ts_barrier" ::: "memory");
  }

  // ---- epilogue: lane-local lsum -> per-row totals, combine, store ----
  lsum += __shfl_xor(lsum, 16, 64);
  lsum += __shfl_xor(lsum, 32, 64);
  // O rows are q = q4*4 + r; row total lives at lane (l15 = q4*4+r, g=0)
  float linv[4];
  #pragma unroll
  for (int r = 0; r < 4; ++r) linv[r] = 1.0f / __shfl(lsum, q4 * 4 + r, 64);

  #pragma unroll
  for (int n = 0; n < 8; ++n) {
    #pragma unroll
    for (int r = 0; r < 4; ++r) {
      const int qg_ = qbase + w * 16 + q4 * 4 + r;
      const int f   = n * 16 + l15;
      float val = O1[n][r] * linv[r] - O2[n][r];
      __builtin_nontemporal_store(val, outp + ((long long)(b * QL + qg_)) * FD + f);
    }
  }
}

extern "C" void kernel_launch(void* const* d_in, const int* in_sizes, int n_in,
                              void* d_out, int out_size, void* d_ws, size_t ws_size,
                              hipStream_t stream) {
  const float* q   = (const float*)d_in[0];
  const float* k   = (const float*)d_in[1];
  const float* v   = (const float*)d_in[2];
  const float* cq  = (const float*)d_in[3];
  const float* ck  = (const float*)d_in[4];
  const int*   am  = (const int*)d_in[5];
  const int*   alm = (const int*)d_in[6];
  const float* bs  = (const float*)d_in[7];
  const float* rm  = (const float*)d_in[8];
  float*       out = (float*)d_out;

  unsigned short* kb = (unsigned short*)d_ws;            // 8 MB bf16 K
  unsigned short* vt = kb + WS_HALF;                     // 8 MB bf16 V^T tiles

  hipLaunchKernelGGL(conv_k,  dim3(WS_HALF / 1024), dim3(256), 0, stream, k, kb);
  hipLaunchKernelGGL(conv_vt, dim3(B_ * 64),        dim3(256), 0, stream, v, vt);

  dim3 grid(B_ * (QL / BQ));   // 512 blocks, 2/CU
  dim3 block(256);
  hipLaunchKernelGGL(alibi_attn, grid, block, 0, stream,
                     kb, vt, q, cq, ck, am, alm, bs, rm, out);
}